// Round 8
// baseline (781.376 us; speedup 1.0000x reference)
//
#include <hip/hip_runtime.h>
#include <hip/hip_bf16.h>
#include <stdint.h>

#define TSTEPS 500
#define BB 32
#define N0 512
#define N1 1024
#define N2 512

typedef unsigned short ushort_t;
typedef __attribute__((ext_vector_type(8))) short short8;
typedef __attribute__((ext_vector_type(4))) float f32x4;

struct TrueT  { static constexpr bool value = true;  };
struct FalseT { static constexpr bool value = false; };

// ---------------- bf16 helpers --------------------------------------------
__device__ __forceinline__ ushort_t f2b(float x) {
    union { float f; uint32_t u; } c; c.f = x;
    uint32_t r = (c.u + 0x7fffu + ((c.u >> 16) & 1u)) >> 16;
    return (ushort_t)r;
}
__device__ __forceinline__ float b2f(ushort_t u) {
    union { uint32_t u; float f; } c; c.u = ((uint32_t)u) << 16;
    return c.f;
}

// ---------------- GLIFR step, algebraically reduced ------------------------
__device__ __forceinline__ float glifr_step(float& v, float& a0, float& a1,
                                            float x) {
    const float INV_I0 = 1.0f / 700.0f;
    const float C2 = 9.43f / 700.0f;
    const float CE = 0.14426950408889634f;
    const float CE10 = 1.4426950408889634f;
    const float C0 = 1.0f - 0.05f * 0.003f;
    const float C1 = 1.0f - 0.05f * 0.1f;
    const float AMP0 = -9.18f, AMP1 = -198.94f;

    float asum = a0 + a1;
    float drv = fmaf(asum, INV_I0, x);
    float e = exp2f(fmaf(v, -CE, CE10));
    float sig = __builtin_amdgcn_rcpf(1.0f + e);
    float na0 = fmaf(sig, a0 + AMP0, a0 * C0);
    float na1 = fmaf(sig, a1 + AMP1, a1 * C1);
    float nv = fmaf(-sig, v, fmaf(-C2, v, v + drv));
    a0 = na0; a1 = na1; v = nv;
    return sig;
}

// ---------------- scan body ------------------------------------------------
#define PD 25
template <int NW, int MODE>
__device__ __forceinline__ void scan_body(const float* __restrict__ drive,
                                          uint32_t* __restrict__ pout,
                                          float* __restrict__ fout, int idx) {
    const int S = BB * NW;

    auto LD = [&](int t) -> float {
        if (MODE == 0) return drive[(size_t)t * S + idx];
        return (t == 0) ? 0.0f : drive[(size_t)(t - 1) * S + idx];
    };

    float v = 0.f, a0 = 0.f, a1 = 0.f;

    auto STEP = [&](int t, float x) {
        float sig = glifr_step(v, a0, a1, x);
        size_t o = (size_t)t * S + idx;
        if (MODE == 2) {
            fout[o] = 20.0f * sig;
        } else {
            ushort_t hi = f2b(sig);
            float lo = sig - b2f(hi);
            pout[o] = (uint32_t)hi | ((uint32_t)f2b(lo) << 16);
        }
    };

    float p[PD];
#pragma unroll
    for (int i = 0; i < PD; ++i) p[i] = LD(i);

    for (int t = 0; t < TSTEPS - PD; t += PD) {
        float q[PD];
#pragma unroll
        for (int i = 0; i < PD; ++i) q[i] = LD(t + PD + i);
#pragma unroll
        for (int i = 0; i < PD; ++i) STEP(t + i, p[i]);
#pragma unroll
        for (int i = 0; i < PD; ++i) p[i] = q[i];
    }
#pragma unroll
    for (int i = 0; i < PD; ++i) STEP(TSTEPS - PD + i, p[i]);
}

// ---------------- scan0 fused with weight split ----------------------------
__global__ void scan0_wsplit(const float* __restrict__ inputs,
                             uint32_t* __restrict__ s0,
                             const float* __restrict__ W1,
                             const float* __restrict__ W2,
                             ushort_t* __restrict__ w1h, ushort_t* __restrict__ w1l,
                             ushort_t* __restrict__ w2h, ushort_t* __restrict__ w2l) {
    const int bid = blockIdx.x;
    if (bid < (BB * N0) / 64) {
        scan_body<N0, 0>(inputs, s0, nullptr, bid * 64 + threadIdx.x);
    } else {
        int i = (bid - (BB * N0) / 64) * 64 + threadIdx.x;
        float a = 20.0f * W1[i];
        ushort_t h = f2b(a);
        w1h[i] = h; w1l[i] = f2b(a - b2f(h));
        float b = 20.0f * W2[i];
        h = f2b(b);
        w2h[i] = h; w2l[i] = f2b(b - b2f(h));
    }
}

template <int NW>
__global__ void scan_mid(const float* __restrict__ drive,
                         uint32_t* __restrict__ sout) {
    scan_body<NW, 1>(drive, sout, nullptr,
                     blockIdx.x * blockDim.x + threadIdx.x);
}

__global__ void scan_last(const float* __restrict__ drive,
                          float* __restrict__ out) {
    scan_body<N2, 2>(drive, nullptr, out,
                     blockIdx.x * blockDim.x + threadIdx.x);
}

// ---------------- K'=3K standard-bf16 MFMA GEMM, counted-vmcnt pipeline ----
// C[M,N] = Ah*Bh^T + Ah*Bl^T + Al*Bh^T as one GEMM over K' = 3K.
// BM=128, BN=128, BK=32, 8 waves, wave-tile 64x32, 32KB LDS (A+B dbuf).
// A: packed u32 (hi|lo<<16) -> regs 2 steps ahead -> v_perm extract -> LDS.
// B: pre-split bf16 planes via global_load_lds, 1 step ahead.
// Raw s_barrier with counted s_waitcnt: A prefetch stays in flight.
template <int NBY, int KC, int LOG>
__global__ __launch_bounds__(512, 8) void gemm_ks(
    const uint32_t* __restrict__ Apk,
    const ushort_t* __restrict__ Bh, const ushort_t* __restrict__ Bl,
    float* __restrict__ C) {
    constexpr int NC = NBY * 128;
    constexpr int KC32 = KC / 32;
    constexpr int KS = 3 * KC32;   // 48 or 96 (even)
    __shared__ char lds[32768];    // A: [0,8K)+[8K,16K) ; B: [16K,24K)+[24K,32K)
    const int tid = threadIdx.x;
    const int lane = tid & 63, wave = tid >> 6;

    // bijective XCD swizzle (m204)
    const int id = blockIdx.x, nwg = gridDim.x;
    const int qq = nwg >> 3, rr = nwg & 7;
    const int xcd = id & 7, jj = id >> 3;
    const int wg = (xcd < rr ? xcd * (qq + 1) : rr * (qq + 1) + (xcd - rr) * qq) + jj;
    const int m0 = (wg / NBY) * 128;
    const int n0 = (wg % NBY) * 128;

    const int wm = wave >> 2, wn = wave & 3;     // wave-tile: rows wm*64, cols wn*32
    const int r4 = lane & 15, kg = lane >> 4;
    const int slot = ((kg ^ ((r4 >> 1) & 3)) * 16);

    // fragment read offsets (round-5 proven zero-conflict geometry)
    const int aRd = (wm * 64 + r4) * 64 + slot;           // + i*1024 + cur*8192
    const int bRd = 16384 + (wn * 32 + r4) * 64 + slot;   // + j*1024 + cur*8192

    // A staging: thread -> row (tid>>2), k-quarter (tid&3); 8 u32 -> 8 bf16
    const int arow = tid >> 2, akq = tid & 3;
    const uint32_t* aSrc = Apk + (size_t)(m0 + arow) * KC + akq * 8;
    const int aWr = arow * 64 + ((akq ^ ((arow >> 1) & 3)) * 16);  // + nxt*8192

    // B staging: 1 global_load_lds per wave, linear dest, pre-swizzled source
    const int brow = n0 + wave * 16 + (lane >> 2);
    const int bchk = ((lane & 3) ^ ((lane >> 3) & 3)) * 16;
    const size_t rowbB = (size_t)KC * 2;
    const size_t bOff = (size_t)brow * rowbB + bchk;
    const int bDst = 16384 + wave * 1024 + lane * 16;     // + nxt*8192

    f32x4 acc[4][2];
#pragma unroll
    for (int i = 0; i < 4; ++i)
#pragma unroll
        for (int j = 0; j < 2; ++j) acc[i][j] = (f32x4){0.f, 0.f, 0.f, 0.f};

    uint4 SA0[2], SA1[2];

    auto issueB = [&](int sTile, int nxt) {
        const int blk = sTile >> LOG;
        const int sk = (sTile & (KC32 - 1)) << 5;
        const char* bp = (blk == 1) ? (const char*)Bl : (const char*)Bh;
        __builtin_amdgcn_global_load_lds(
            (const __attribute__((address_space(1))) uint32_t*)(bp + bOff + (size_t)sk * 2),
            (__attribute__((address_space(3))) uint32_t*)(lds + bDst + nxt * 8192),
            16, 0, 0);
    };
    auto loadA = [&](int sTile, uint4* S) {
        const uint32_t* p = aSrc + ((sTile & (KC32 - 1)) << 5);
        S[0] = *reinterpret_cast<const uint4*>(p);
        S[1] = *reinterpret_cast<const uint4*>(p + 4);
    };
    auto writeA = [&](const uint4* S, uint32_t sel, int nxt) {
        uint4 w;
        w.x = __builtin_amdgcn_perm(S[0].y, S[0].x, sel);
        w.y = __builtin_amdgcn_perm(S[0].w, S[0].z, sel);
        w.z = __builtin_amdgcn_perm(S[1].y, S[1].x, sel);
        w.w = __builtin_amdgcn_perm(S[1].w, S[1].z, sel);
        *reinterpret_cast<uint4*>(lds + nxt * 8192 + aWr) = w;
    };
    auto compute = [&](int cur) {
        short8 a[4], b[2];
#pragma unroll
        for (int i = 0; i < 4; ++i)
            a[i] = *(const short8*)(lds + cur * 8192 + aRd + i * 1024);
#pragma unroll
        for (int j = 0; j < 2; ++j)
            b[j] = *(const short8*)(lds + cur * 8192 + bRd + j * 1024);
        __builtin_amdgcn_s_setprio(1);
#pragma unroll
        for (int i = 0; i < 4; ++i)
#pragma unroll
            for (int j = 0; j < 2; ++j)
                acc[i][j] = __builtin_amdgcn_mfma_f32_16x16x32_bf16(
                    a[i], b[j], acc[i][j], 0, 0, 0);
        __builtin_amdgcn_s_setprio(0);
    };

    // step s: reads bufs s&1; issues B(s+1)->nxt; loads A(s+2)->Sld;
    // writes A(s+1) (in Swr) -> Abuf nxt; counted wait leaves A(s+2) in flight.
    auto step = [&](int s, uint4* Swr, uint4* Sld, auto hasA) {
        const int cur = s & 1, nxt = cur ^ 1;
        issueB(s + 1, nxt);
        __builtin_amdgcn_sched_barrier(0);   // pin: B issued before A loads
        if constexpr (decltype(hasA)::value) loadA(s + 2, Sld);
        compute(cur);
        const uint32_t sel = (((s + 1) >> LOG) < 2) ? 0x05040100u : 0x07060302u;
        writeA(Swr, sel, nxt);
        __builtin_amdgcn_sched_barrier(0);
        if constexpr (decltype(hasA)::value)
            asm volatile("s_waitcnt vmcnt(2) lgkmcnt(0)" ::: "memory");
        else
            asm volatile("s_waitcnt vmcnt(0) lgkmcnt(0)" ::: "memory");
        __builtin_amdgcn_s_barrier();
    };

    // prologue: B(0)->buf0, A(0)->SA0, A(1)->SA1, write A(0)->Abuf0
    issueB(0, 0);
    __builtin_amdgcn_sched_barrier(0);
    loadA(0, SA0);
    loadA(1, SA1);
    writeA(SA0, 0x05040100u, 0);
    __builtin_amdgcn_sched_barrier(0);
    asm volatile("s_waitcnt vmcnt(2) lgkmcnt(0)" ::: "memory");
    __builtin_amdgcn_s_barrier();

    for (int s = 0; s < KS - 2; s += 2) {
        step(s,     SA1, SA0, TrueT{});
        step(s + 1, SA0, SA1, TrueT{});
    }
    step(KS - 2, SA1, SA0, FalseT{});
    compute((KS - 1) & 1);

    // epilogue: C/D layout col=lane&15, row=(lane>>4)*4+reg
#pragma unroll
    for (int i = 0; i < 4; ++i)
#pragma unroll
        for (int j = 0; j < 2; ++j)
#pragma unroll
            for (int r = 0; r < 4; ++r) {
                int row = m0 + wm * 64 + i * 16 + kg * 4 + r;
                int col = n0 + wn * 32 + j * 16 + r4;
                C[(size_t)row * NC + col] = acc[i][j][r];
            }
}

extern "C" void kernel_launch(void* const* d_in, const int* in_sizes, int n_in,
                              void* d_out, int out_size, void* d_ws,
                              size_t ws_size, hipStream_t stream) {
    const float* inputs = (const float*)d_in[0];  // [500,32,512]
    const float* W1 = (const float*)d_in[1];      // [1024,512]
    const float* W2 = (const float*)d_in[2];      // [512,1024]
    float* out = (float*)d_out;                   // [500,32,512]
    char* ws = (char*)d_ws;

    // workspace (bytes):
    //  region A [0, 65,536,000): s0 packed u32 (32.77MB); later s1 packed (65.54MB)
    //  region B [65,536,000, 131,072,000): x1 f32 (65.54MB); later x2 f32
    //  weights  [131,072,000, 135,266,304): w1h w1l w2h w2l (1MB each)
    uint32_t* s0 = (uint32_t*)ws;
    uint32_t* s1 = (uint32_t*)ws;             // s0 dead after gemm1
    float*    x1 = (float*)(ws + 65536000);
    float*    x2 = (float*)(ws + 65536000);   // x1 dead after scan1
    ushort_t* w1h = (ushort_t*)(ws + 131072000);
    ushort_t* w1l = (ushort_t*)(ws + 132120576);
    ushort_t* w2h = (ushort_t*)(ws + 133169152);
    ushort_t* w2l = (ushort_t*)(ws + 134217728);

    // 1) layer-0 recurrence -> packed sigma, fused with weight split
    scan0_wsplit<<<256 + 8192, 64, 0, stream>>>(inputs, s0, W1, W2,
                                                w1h, w1l, w2h, w2l);
    // 2) X1 = S0 @ (20*W1)^T -> f32 [16000,1024]; 125x8 tiles
    gemm_ks<8, N0, 4><<<1000, 512, 0, stream>>>(s0, w1h, w1l, x1);
    // 3) layer-1 recurrence -> packed sigma
    scan_mid<N1><<<512, 64, 0, stream>>>(x1, s1);
    // 4) X2 = S1 @ (20*W2)^T -> f32 [16000,512]; 125x4 tiles
    gemm_ks<4, N1, 5><<<500, 512, 0, stream>>>(s1, w2h, w2l, x2);
    // 5) layer-2 recurrence -> spikes (20*sigma) -> out
    scan_last<<<256, 64, 0, stream>>>(x2, out);
}

// Round 9
// 202.056 us; speedup vs baseline: 3.8671x; 3.8671x over previous
//
#include <hip/hip_runtime.h>
#include <hip/hip_bf16.h>
#include <stdint.h>

#define TSTEPS 500
#define BB 32
#define N0 512
#define N1 1024
#define N2 512

typedef unsigned short ushort_t;
typedef __attribute__((ext_vector_type(8))) short short8;
typedef __attribute__((ext_vector_type(4))) float f32x4;

// ---------------- bf16 helpers --------------------------------------------
__device__ __forceinline__ ushort_t f2b(float x) {
    union { float f; uint32_t u; } c; c.f = x;
    uint32_t r = (c.u + 0x7fffu + ((c.u >> 16) & 1u)) >> 16;
    return (ushort_t)r;
}
__device__ __forceinline__ float b2f(ushort_t u) {
    union { uint32_t u; float f; } c; c.u = ((uint32_t)u) << 16;
    return c.f;
}

// ---------------- GLIFR step, algebraically reduced ------------------------
__device__ __forceinline__ float glifr_step(float& v, float& a0, float& a1,
                                            float x) {
    const float INV_I0 = 1.0f / 700.0f;
    const float C2 = 9.43f / 700.0f;
    const float CE = 0.14426950408889634f;
    const float CE10 = 1.4426950408889634f;
    const float C0 = 1.0f - 0.05f * 0.003f;
    const float C1 = 1.0f - 0.05f * 0.1f;
    const float AMP0 = -9.18f, AMP1 = -198.94f;

    float asum = a0 + a1;
    float drv = fmaf(asum, INV_I0, x);
    float e = exp2f(fmaf(v, -CE, CE10));
    float sig = __builtin_amdgcn_rcpf(1.0f + e);
    float na0 = fmaf(sig, a0 + AMP0, a0 * C0);
    float na1 = fmaf(sig, a1 + AMP1, a1 * C1);
    float nv = fmaf(-sig, v, fmaf(-C2, v, v + drv));
    a0 = na0; a1 = na1; v = nv;
    return sig;
}

// ---------------- scan body: f32 drive in, packed(hi|lo<<16) or f32 out ----
// Pack is truncation-split: low16 = sig>>16 (trunc bf16), high16 = trunc bf16
// of the residual. hi+lo represents sig to ~2^-18 (same as RNE split).
#define PD 25
template <int NW, int MODE>
__device__ __forceinline__ void scan_body(const float* __restrict__ drive,
                                          uint32_t* __restrict__ pout,
                                          float* __restrict__ fout, int idx) {
    const int S = BB * NW;

    auto LD = [&](int t) -> float {
        if (MODE == 0) return drive[(size_t)t * S + idx];
        return (t == 0) ? 0.0f : drive[(size_t)(t - 1) * S + idx];
    };

    float v = 0.f, a0 = 0.f, a1 = 0.f;

    auto STEP = [&](int t, float x) {
        float sig = glifr_step(v, a0, a1, x);
        size_t o = (size_t)t * S + idx;
        if (MODE == 2) {
            fout[o] = 20.0f * sig;
        } else {
            uint32_t su = __float_as_uint(sig);
            float lo = sig - __uint_as_float(su & 0xffff0000u);
            pout[o] = (su >> 16) | (__float_as_uint(lo) & 0xffff0000u);
        }
    };

    float p[PD];
#pragma unroll
    for (int i = 0; i < PD; ++i) p[i] = LD(i);

    for (int t = 0; t < TSTEPS - PD; t += PD) {
        float q[PD];
#pragma unroll
        for (int i = 0; i < PD; ++i) q[i] = LD(t + PD + i);
#pragma unroll
        for (int i = 0; i < PD; ++i) STEP(t + i, p[i]);
#pragma unroll
        for (int i = 0; i < PD; ++i) p[i] = q[i];
    }
#pragma unroll
    for (int i = 0; i < PD; ++i) STEP(TSTEPS - PD + i, p[i]);
}

// ---------------- scan0 fused with weight split ----------------------------
__global__ void scan0_wsplit(const float* __restrict__ inputs,
                             uint32_t* __restrict__ s0,
                             const float* __restrict__ W1,
                             const float* __restrict__ W2,
                             ushort_t* __restrict__ w1h, ushort_t* __restrict__ w1l,
                             ushort_t* __restrict__ w2h, ushort_t* __restrict__ w2l) {
    const int bid = blockIdx.x;
    if (bid < (BB * N0) / 64) {
        scan_body<N0, 0>(inputs, s0, nullptr, bid * 64 + threadIdx.x);
    } else {
        int i = (bid - (BB * N0) / 64) * 64 + threadIdx.x;
        float a = 20.0f * W1[i];
        ushort_t h = f2b(a);
        w1h[i] = h; w1l[i] = f2b(a - b2f(h));
        float b = 20.0f * W2[i];
        h = f2b(b);
        w2h[i] = h; w2l[i] = f2b(b - b2f(h));
    }
}

template <int NW>
__global__ void scan_mid(const float* __restrict__ drive,
                         uint32_t* __restrict__ sout) {
    scan_body<NW, 1>(drive, sout, nullptr,
                     blockIdx.x * blockDim.x + threadIdx.x);
}

__global__ void scan_last(const float* __restrict__ drive,
                          float* __restrict__ out) {
    scan_body<N2, 2>(drive, nullptr, out,
                     blockIdx.x * blockDim.x + threadIdx.x);
}

// ---------------- bf16x3-split MFMA GEMM, deep-pipelined -------------------
// C[M,N] = A[M,K]*B[N,K]^T, A packed u32 (hi|lo<<16), B pre-split planes.
// 128x128 tile, BK=32, 4 waves. LDS 80KB: A double-buf (2x16KB: Ah+Al),
// B triple-buf (3x16KB: Bh+Bl). Per phase s: issue B(s+2) glds, load A(s+2)
// to regs, compute(s), v_perm-split + ds_write A(s+1), then
// lgkmcnt(0)-only raw barrier. B loads get ~2 phases in flight; the
// compiler's consumption wait before writeA (its A-regs are younger in the
// VMEM queue than B(s+1)) transitively guarantees B(s+1) completion at the
// barrier — counted vmcnt for free, never a full drain.
template <int NBY, int KC>
__global__ __launch_bounds__(256, 2) void gemm_x3(
    const uint32_t* __restrict__ Apk,
    const ushort_t* __restrict__ Bh, const ushort_t* __restrict__ Bl,
    float* __restrict__ C) {
    constexpr int NC = NBY * 128;
    constexpr int KSTEPS = KC / 32;   // 16 or 32 (even)
    __shared__ char lds[81920];       // A: 2x16KB @0 ; B: 3x16KB @32768
    const int tid = threadIdx.x;
    const int lane = tid & 63, wave = tid >> 6;

    // bijective XCD swizzle (m204)
    const int id = blockIdx.x, nwg = gridDim.x;
    const int qq = nwg >> 3, rr = nwg & 7;
    const int xcd = id & 7, jj = id >> 3;
    const int wg = (xcd < rr ? xcd * (qq + 1) : rr * (qq + 1) + (xcd - rr) * qq) + jj;
    const int m0 = (wg / NBY) * 128;
    const int n0 = (wg % NBY) * 128;

    // B staging (waves 2,3): pre-swizzled global source, linear LDS dest
    const ushort_t* gB = (wave == 2) ? Bh : Bl;
    const int chunk_sw = (lane & 3) ^ ((lane >> 3) & 3);
    const size_t rowbB = (size_t)KC * 2;
    const char* gsrcB = (const char*)gB +
                        (size_t)(n0 + (lane >> 2)) * rowbB + (size_t)chunk_sw * 16;

    // A staging (all 256 threads): 4 x uint4 (16 packed elems) per K-tile
    const int r0 = tid >> 3, c4 = tid & 7;
    const int ch = (c4 >> 1) ^ ((r0 >> 1) & 3);     // swizzled 16B slot
    const int aoff = r0 * 64 + ch * 16 + (c4 & 1) * 8;
    const uint32_t* aSrc = Apk + (size_t)(m0 + r0) * KC + c4 * 4;

    const int wm = wave >> 1, wn = wave & 1;
    const int r4 = lane & 15, kg = lane >> 4;
    const int slot = kg ^ ((r4 >> 1) & 3);
    const int fA = (wm * 64 + r4) * 64 + slot * 16;
    const int fB = (wn * 64 + r4) * 64 + slot * 16;

    f32x4 acc[4][4];
#pragma unroll
    for (int i = 0; i < 4; ++i)
#pragma unroll
        for (int j = 0; j < 4; ++j) acc[i][j] = (f32x4){0.f, 0.f, 0.f, 0.f};

    auto issueB = [&](int ks, int bbuf) {
        if (wave >= 2) {
#pragma unroll
            for (int i = 0; i < 8; ++i) {
                __builtin_amdgcn_global_load_lds(
                    (const __attribute__((address_space(1))) uint32_t*)(
                        gsrcB + (size_t)i * 16 * rowbB + (size_t)ks * 64),
                    (__attribute__((address_space(3))) uint32_t*)(
                        lds + 32768 + bbuf * 16384 + (wave - 2) * 8192 + i * 1024),
                    16, 0, 0);
            }
        }
    };
    auto loadA = [&](int ks, uint4* R) {
#pragma unroll
        for (int i = 0; i < 4; ++i)
            R[i] = *reinterpret_cast<const uint4*>(
                aSrc + (size_t)i * 32 * KC + (size_t)ks * 32);
    };
    auto writeA = [&](const uint4* R, int abuf) {
#pragma unroll
        for (int i = 0; i < 4; ++i) {
            uint32_t hi01 = __builtin_amdgcn_perm(R[i].y, R[i].x, 0x05040100u);
            uint32_t lo01 = __builtin_amdgcn_perm(R[i].y, R[i].x, 0x07060302u);
            uint32_t hi23 = __builtin_amdgcn_perm(R[i].w, R[i].z, 0x05040100u);
            uint32_t lo23 = __builtin_amdgcn_perm(R[i].w, R[i].z, 0x07060302u);
            *reinterpret_cast<uint2*>(lds + abuf * 16384 + aoff + i * 2048) =
                make_uint2(hi01, hi23);
            *reinterpret_cast<uint2*>(lds + abuf * 16384 + 8192 + aoff + i * 2048) =
                make_uint2(lo01, lo23);
        }
    };
    auto compute = [&](int abuf, int bbuf) {
        short8 ah[4], al[4], bh[4], bl[4];
#pragma unroll
        for (int i = 0; i < 4; ++i) {
            ah[i] = *(const short8*)(lds + abuf * 16384 + fA + i * 1024);
            al[i] = *(const short8*)(lds + abuf * 16384 + 8192 + fA + i * 1024);
            bh[i] = *(const short8*)(lds + 32768 + bbuf * 16384 + fB + i * 1024);
            bl[i] = *(const short8*)(lds + 32768 + bbuf * 16384 + 8192 + fB + i * 1024);
        }
#pragma unroll
        for (int i = 0; i < 4; ++i)
#pragma unroll
            for (int j = 0; j < 4; ++j) {
                acc[i][j] = __builtin_amdgcn_mfma_f32_16x16x32_bf16(
                    ah[i], bh[j], acc[i][j], 0, 0, 0);
                acc[i][j] = __builtin_amdgcn_mfma_f32_16x16x32_bf16(
                    ah[i], bl[j], acc[i][j], 0, 0, 0);
                acc[i][j] = __builtin_amdgcn_mfma_f32_16x16x32_bf16(
                    al[i], bh[j], acc[i][j], 0, 0, 0);
            }
    };
    auto bar = [&]() {
        asm volatile("s_waitcnt lgkmcnt(0)" ::: "memory");
        __builtin_amdgcn_s_barrier();
        __builtin_amdgcn_sched_barrier(0);
    };

    uint4 R0[4], R1[4];
    // prologue: B(0)->Bbuf0, B(1)->Bbuf1; A(0)->R0, A(1)->R1; A(0)->Abuf0
    issueB(0, 0);
    issueB(1, 1);
    loadA(0, R0);
    loadA(1, R1);
    writeA(R0, 0);   // implicit vmcnt wait retires B(0),B(1),A(0)
    bar();

    int cB = 0;  // B-buf of tile s (s even at loop top)
    for (int s = 0; s + 3 < KSTEPS; s += 2) {
        int cB1 = cB + 1; if (cB1 == 3) cB1 = 0;
        int cB2 = cB1 + 1; if (cB2 == 3) cB2 = 0;
        // phase s (even, abuf 0)
        issueB(s + 2, cB2);
        loadA(s + 2, R0);
        compute(0, cB);
        writeA(R1, 1);   // A(s+1) -> abuf1; retires B(s+1)+A(s+1)
        bar();
        // phase s+1 (odd, abuf 1)
        issueB(s + 3, cB);
        loadA(s + 3, R1);
        compute(1, cB1);
        writeA(R0, 0);   // A(s+2) -> abuf0; retires B(s+2)+A(s+2)
        bar();
        cB = cB2;
    }
    int cB1 = cB + 1; if (cB1 == 3) cB1 = 0;
    // phase KSTEPS-2 (even)
    compute(0, cB);
    writeA(R1, 1);       // A(KSTEPS-1) -> abuf1; retires B(KSTEPS-1)
    bar();
    // phase KSTEPS-1 (odd)
    compute(1, cB1);

    // epilogue: C/D layout col=lane&15, row=(lane>>4)*4+reg
#pragma unroll
    for (int i = 0; i < 4; ++i)
#pragma unroll
        for (int j = 0; j < 4; ++j)
#pragma unroll
            for (int r = 0; r < 4; ++r) {
                int row = m0 + wm * 64 + i * 16 + kg * 4 + r;
                int col = n0 + wn * 64 + j * 16 + r4;
                C[(size_t)row * NC + col] = acc[i][j][r];
            }
}

extern "C" void kernel_launch(void* const* d_in, const int* in_sizes, int n_in,
                              void* d_out, int out_size, void* d_ws,
                              size_t ws_size, hipStream_t stream) {
    const float* inputs = (const float*)d_in[0];  // [500,32,512]
    const float* W1 = (const float*)d_in[1];      // [1024,512]
    const float* W2 = (const float*)d_in[2];      // [512,1024]
    float* out = (float*)d_out;                   // [500,32,512]
    char* ws = (char*)d_ws;

    // workspace (bytes):
    //  region A [0, 65,536,000): s0 packed u32 (32.77MB); later s1 packed (65.54MB)
    //  region B [65,536,000, 131,072,000): x1 f32 (65.54MB); later x2 f32
    //  weights  [131,072,000, 135,266,304): w1h w1l w2h w2l (1MB each)
    uint32_t* s0 = (uint32_t*)ws;
    uint32_t* s1 = (uint32_t*)ws;             // s0 dead after gemm1
    float*    x1 = (float*)(ws + 65536000);
    float*    x2 = (float*)(ws + 65536000);   // x1 dead after scan1
    ushort_t* w1h = (ushort_t*)(ws + 131072000);
    ushort_t* w1l = (ushort_t*)(ws + 132120576);
    ushort_t* w2h = (ushort_t*)(ws + 133169152);
    ushort_t* w2l = (ushort_t*)(ws + 134217728);

    // 1) layer-0 recurrence -> packed sigma, fused with weight split
    scan0_wsplit<<<256 + 8192, 64, 0, stream>>>(inputs, s0, W1, W2,
                                                w1h, w1l, w2h, w2l);
    // 2) X1 = S0 @ (20*W1)^T -> f32 [16000,1024]
    gemm_x3<8, N0><<<1000, 256, 0, stream>>>(s0, w1h, w1l, x1);
    // 3) layer-1 recurrence -> packed sigma
    scan_mid<N1><<<512, 64, 0, stream>>>(x1, s1);
    // 4) X2 = S1 @ (20*W2)^T -> f32 [16000,512]
    gemm_x3<4, N1><<<500, 256, 0, stream>>>(s1, w2h, w2l, x2);
    // 5) layer-2 recurrence -> spikes (20*sigma) -> out
    scan_last<<<256, 64, 0, stream>>>(x2, out);
}